// Round 4
// baseline (396.537 us; speedup 1.0000x reference)
//
#include <hip/hip_runtime.h>
#include <hip/hip_bf16.h>

#define TOKENS 16384
#define DIM 1024
#define HID 4096

typedef __attribute__((ext_vector_type(8))) short short8;
typedef __attribute__((ext_vector_type(4))) float f32x4;

__device__ __forceinline__ unsigned short f2bf(float f) {
  union { float f; unsigned int u; } v; v.f = f;
  unsigned int r = v.u + 0x7fffu + ((v.u >> 16) & 1u);
  return (unsigned short)(r >> 16);
}

__device__ __forceinline__ void async16(const void* g, void* lds) {
  __builtin_amdgcn_global_load_lds((const __attribute__((address_space(1))) void*)g,
                                   (__attribute__((address_space(3))) void*)lds, 16, 0, 0);
}

// ---------------------------------------------------------------------------
// Router: 16 tokens/block, fp64 logits; selected -> xb bf16, else -> out fp32.
// ---------------------------------------------------------------------------
__global__ __launch_bounds__(256) void router_kernel(
    const float* __restrict__ x, const float* __restrict__ Wr, const float* __restrict__ br,
    float* __restrict__ out, unsigned short* __restrict__ xb,
    int* __restrict__ idx, int* __restrict__ counter)
{
  __shared__ unsigned char selLds[16];
  int wid = threadIdx.x >> 6, lane = threadIdx.x & 63;
  const float4* wr4 = (const float4*)Wr;
  float4 w[4];
#pragma unroll
  for (int j = 0; j < 4; ++j) w[j] = wr4[lane + 64 * j];
  float b0 = br[0];

#pragma unroll
  for (int t = 0; t < 4; ++t) {
    int token = blockIdx.x * 16 + wid * 4 + t;
    const float4* xr = (const float4*)(x + (size_t)token * DIM);
    float4 v[4];
#pragma unroll
    for (int j = 0; j < 4; ++j) v[j] = xr[lane + 64 * j];
    double s = 0.0;
#pragma unroll
    for (int j = 0; j < 4; ++j)
      s += (double)v[j].x * w[j].x + (double)v[j].y * w[j].y +
           (double)v[j].z * w[j].z + (double)v[j].w * w[j].w;
#pragma unroll
    for (int off = 32; off > 0; off >>= 1) s += __shfl_xor(s, off);
    bool sel = ((float)s + b0) > 0.0f;          // sigmoid(logit) > 0.5
    if (sel) {
      ushort4* xbr = (ushort4*)(xb + (size_t)token * DIM);
#pragma unroll
      for (int j = 0; j < 4; ++j) {
        ushort4 u;
        u.x = f2bf(v[j].x); u.y = f2bf(v[j].y); u.z = f2bf(v[j].z); u.w = f2bf(v[j].w);
        xbr[lane + 64 * j] = u;
      }
    } else {
      float4* outr = (float4*)(out + (size_t)token * DIM);
#pragma unroll
      for (int j = 0; j < 4; ++j) outr[lane + 64 * j] = v[j];
    }
    if (lane == 0) selLds[wid * 4 + t] = sel ? 1 : 0;
  }
  __syncthreads();
  if (threadIdx.x == 0) {
    int cnt = 0;
#pragma unroll
    for (int i = 0; i < 16; ++i) cnt += selLds[i];
    int p = atomicAdd(counter, cnt);
#pragma unroll
    for (int i = 0; i < 16; ++i)
      if (selLds[i]) idx[p++] = blockIdx.x * 16 + i;
  }
}

// ---------------------------------------------------------------------------
// Transpose + fp32->bf16 cast: W [R][C] fp32 -> Wt [C][R] bf16.
// ---------------------------------------------------------------------------
__global__ __launch_bounds__(256) void transpose_cast_kernel(
    const float* __restrict__ W, unsigned short* __restrict__ Wt, int R, int C)
{
  __shared__ float tile[32][33];
  int tx = threadIdx.x & 31, ty = threadIdx.x >> 5;
  int c0 = blockIdx.x * 32, r0 = blockIdx.y * 32;
#pragma unroll
  for (int i = 0; i < 32; i += 8)
    tile[ty + i][tx] = W[(size_t)(r0 + ty + i) * C + (c0 + tx)];
  __syncthreads();
#pragma unroll
  for (int i = 0; i < 32; i += 8)
    Wt[(size_t)(c0 + ty + i) * R + (r0 + tx)] = f2bf(tile[tx][ty + i]);
}

__global__ void frac_kernel(const int* __restrict__ counter, float* __restrict__ fr)
{
  fr[0] = (float)(*counter) * (1.0f / (float)TOKENS);
}

// ---------------------------------------------------------------------------
// 256x256 8-phase bf16 GEMM (T2+T3+T4+T5 port, conservative schedule).
// 8 waves (512 thr); per phase: block computes one 128x128 C-quadrant x K=64.
// LDS (dynamic 132096 B): As[2][2][128][64], Bs[2][2][128][64], rowIdx[256].
// Half-tile stream per K-tile t: h(4t+0)=A0 h(4t+1)=B0 h(4t+2)=B1 h(4t+3)=A1.
// Phase p stages h(p+6); vmcnt(4) at each K-tile's last phase (vmcnt(0) tail).
// T2 swizzle: LDS[row][c] holds logical (row, c ^ ((row&7)<<3)) via
// pre-swizzled global source (linear gload_lds dest) + swizzled ds_read.
// ---------------------------------------------------------------------------
template<int N, int K, bool FIRST>
__global__ __launch_bounds__(512, 2) void gemm8_kernel(
    const unsigned short* __restrict__ A, const unsigned short* __restrict__ Bt,
    const float* __restrict__ bias, const int* __restrict__ idxp,
    const int* __restrict__ counter,
    unsigned short* __restrict__ Hout, float* __restrict__ Cout)
{
  constexpr int NT = N / 256;            // column tiles
  constexpr int NKT = K / 64;            // K-tiles
  constexpr int NH = NKT * 4;            // half-tile stream length

  int xcd = blockIdx.x & 7, lin = blockIdx.x >> 3;
  int rowb = (lin / NT) * 8 + xcd;       // row-tiles round-robin XCDs
  int colb = lin % NT;                   // col-fast within XCD chunk

  int cnt = *counter;
  int row0 = rowb * 256;
  if (row0 >= cnt) return;
  int col0 = colb * 256;

  extern __shared__ unsigned short smem[];
  unsigned short* As = smem;             // [2][2][128][64]
  unsigned short* Bs = smem + 32768;
  int* rowIdxL = (int*)(smem + 65536);   // 256 ints

  int tid = threadIdx.x, w = tid >> 6, lane = tid & 63;
  if (tid < 256) rowIdxL[tid] = idxp[row0 + tid];
  __syncthreads();

  // ---- staging precompute: per thread 2 loads/half-tile, pre-swizzled src
  int rbase = w * 8 + (lane >> 3);                 // row (mod 64-block) this lane stages
  int colp  = 8 * ((lane & 7) ^ (lane >> 3));      // pre-swizzled k offset (shorts)
  const unsigned short* gAp[2][2];                 // [half][L]
  const unsigned short* gBp[2][2];
#pragma unroll
  for (int hf = 0; hf < 2; ++hf)
#pragma unroll
    for (int L = 0; L < 2; ++L) {
      int r = hf * 128 + L * 64 + rbase;
      int arow = FIRST ? rowIdxL[r] : (row0 + r);
      gAp[hf][L] = A  + (size_t)arow * K + colp;
      gBp[hf][L] = Bt + (size_t)(col0 + r) * K + colp;
    }

  // stream element n -> (arr, half): 0->(A,0) 1->(B,0) 2->(B,1) 3->(A,1)
  auto stage_half = [&](int n) {
    int T = n >> 2, j = n & 3;
    int half = j >> 1;
    bool isA = (j == 0) || (j == 3);
    unsigned short* base =
        (isA ? As : Bs) + (size_t)((T & 1) * 16384 + half * 8192 + w * 512);
    const unsigned short* s0 = (isA ? gAp[half][0] : gBp[half][0]) + T * 64;
    const unsigned short* s1 = (isA ? gAp[half][1] : gBp[half][1]) + T * 64;
    async16(s0, base);
    async16(s1, base + 4096);
  };

  f32x4 acc[4][4][2];
#pragma unroll
  for (int q = 0; q < 4; ++q)
#pragma unroll
    for (int mi = 0; mi < 4; ++mi)
#pragma unroll
      for (int ni = 0; ni < 2; ++ni) acc[q][mi][ni] = (f32x4){0.f, 0.f, 0.f, 0.f};

  // wave position inside the 128x128 phase-quadrant: 2 x 4 waves of 64x32
  int qr = (w >> 2) * 64, qc = (w & 3) * 32;
  int fr = lane & 15, khalf = lane >> 4;

  // ---- prologue: stage h0..h5, land K-tile 0, keep 2 half-tiles in flight
#pragma unroll
  for (int n = 0; n < 6; ++n) stage_half(n);
  asm volatile("s_waitcnt vmcnt(4)" ::: "memory");
  __builtin_amdgcn_s_barrier();

  // ---- main loop: NKT K-tiles x 4 phases
  for (int t = 0; t < NKT; ++t) {
    int buf = t & 1;
#pragma unroll
    for (int q = 0; q < 4; ++q) {
      const int ah = q >> 1, bh = q & 1;
      unsigned short* Abase = As + (size_t)(buf * 16384 + ah * 8192);
      unsigned short* Bbase = Bs + (size_t)(buf * 16384 + bh * 8192);
      short8 af[4][2], bfr[2][2];
#pragma unroll
      for (int mi = 0; mi < 4; ++mi)
#pragma unroll
        for (int s = 0; s < 2; ++s) {
          int row = qr + mi * 16 + fr;
          af[mi][s] = *(const short8*)&Abase[row * 64 +
                        ((s * 32 + khalf * 8) ^ ((row & 7) << 3))];
        }
#pragma unroll
      for (int ni = 0; ni < 2; ++ni)
#pragma unroll
        for (int s = 0; s < 2; ++s) {
          int row = qc + ni * 16 + fr;
          bfr[ni][s] = *(const short8*)&Bbase[row * 64 +
                        ((s * 32 + khalf * 8) ^ ((row & 7) << 3))];
        }
      int n = t * 4 + q + 6;
      if (n < NH) stage_half(n);
      __builtin_amdgcn_s_barrier();
      asm volatile("s_waitcnt lgkmcnt(0)" ::: "memory");
      __builtin_amdgcn_sched_barrier(0);
      __builtin_amdgcn_s_setprio(1);
#pragma unroll
      for (int mi = 0; mi < 4; ++mi)
#pragma unroll
        for (int ni = 0; ni < 2; ++ni)
#pragma unroll
          for (int s = 0; s < 2; ++s)
            acc[q][mi][ni] = __builtin_amdgcn_mfma_f32_16x16x32_bf16(
                af[mi][s], bfr[ni][s], acc[q][mi][ni], 0, 0, 0);
      __builtin_amdgcn_s_setprio(0);
      __builtin_amdgcn_sched_barrier(0);
      if (q == 3 && t < NKT - 1) {
        if (t < NKT - 2) { asm volatile("s_waitcnt vmcnt(4)" ::: "memory"); }
        else             { asm volatile("s_waitcnt vmcnt(0)" ::: "memory"); }
        __builtin_amdgcn_sched_barrier(0);
      }
      __builtin_amdgcn_s_barrier();
    }
  }

  // ---- epilogue: C/D layout col = lane&15, row = (lane>>4)*4 + reg
  int cl = lane & 15, rq = lane >> 4;
#pragma unroll
  for (int q = 0; q < 4; ++q) {
    const int ah = q >> 1, bh = q & 1;
#pragma unroll
    for (int mi = 0; mi < 4; ++mi) {
#pragma unroll
      for (int ni = 0; ni < 2; ++ni) {
        int col = col0 + bh * 128 + qc + ni * 16 + cl;
        float bv = bias[col];
#pragma unroll
        for (int r2 = 0; r2 < 4; ++r2) {
          int rloc = ah * 128 + qr + mi * 16 + rq * 4 + r2;
          int grow = row0 + rloc;
          float val = acc[q][mi][ni][r2] + bv;
          if (FIRST) {
            val = val > 0.f ? val : 0.f;
            Hout[(size_t)grow * N + col] = f2bf(val);
          } else if (grow < cnt) {
            int tok = rowIdxL[rloc];
            Cout[(size_t)tok * DIM + col] = val;
          }
        }
      }
    }
  }
}

// ---------------------------------------------------------------------------
extern "C" void kernel_launch(void* const* d_in, const int* in_sizes, int n_in,
                              void* d_out, int out_size, void* d_ws, size_t ws_size,
                              hipStream_t stream)
{
  const float* x  = (const float*)d_in[0];
  const float* Wr = (const float*)d_in[1];
  const float* br = (const float*)d_in[2];
  const float* W1 = (const float*)d_in[3];
  const float* b1 = (const float*)d_in[4];
  const float* W2 = (const float*)d_in[5];
  const float* b2 = (const float*)d_in[6];
  float* out = (float*)d_out;

  char* ws = (char*)d_ws;
  int* counter        = (int*)ws;                               // 4 B (zeroed)
  int* idx            = (int*)(ws + 256);                       // 64 KB (zeroed)
  unsigned short* xb  = (unsigned short*)(ws + (1ull  << 20));  // 32 MB bf16 x
  unsigned short* W1T = (unsigned short*)(ws + (34ull << 20));  // 8 MB  W1^T [4096][1024]
  unsigned short* W2T = (unsigned short*)(ws + (44ull << 20));  // 8 MB  W2^T [1024][4096]
  unsigned short* h   = (unsigned short*)(ws + (54ull << 20));  // 128 MB bf16 h

  constexpr int LDS_BYTES = 132096;
  hipFuncSetAttribute(reinterpret_cast<const void*>(&gemm8_kernel<HID, DIM, true>),
                      hipFuncAttributeMaxDynamicSharedMemorySize, LDS_BYTES);
  hipFuncSetAttribute(reinterpret_cast<const void*>(&gemm8_kernel<DIM, HID, false>),
                      hipFuncAttributeMaxDynamicSharedMemorySize, LDS_BYTES);

  hipMemsetAsync(ws, 0, 256 + TOKENS * 4, stream);  // counter + idx

  router_kernel<<<TOKENS / 16, 256, 0, stream>>>(x, Wr, br, out, xb, idx, counter);
  transpose_cast_kernel<<<dim3(HID / 32, DIM / 32), 256, 0, stream>>>(W1, W1T, DIM, HID);
  transpose_cast_kernel<<<dim3(DIM / 32, HID / 32), 256, 0, stream>>>(W2, W2T, HID, DIM);
  frac_kernel<<<1, 1, 0, stream>>>(counter, out + (size_t)TOKENS * DIM);

  gemm8_kernel<HID, DIM, true><<<(HID / 256) * (TOKENS / 256), 512, LDS_BYTES, stream>>>(
      xb, W1T, b1, idx, counter, h, nullptr);
  gemm8_kernel<DIM, HID, false><<<(DIM / 256) * (TOKENS / 256), 512, LDS_BYTES, stream>>>(
      h, W2T, b2, idx, counter, nullptr, out);
}